// Round 1
// baseline (6403.687 us; speedup 1.0000x reference)
//
#include <hip/hip_runtime.h>

typedef _Float16 half2v __attribute__((ext_vector_type(2)));
typedef _Float16 half8v __attribute__((ext_vector_type(8)));
typedef float f32x4 __attribute__((ext_vector_type(4)));

#define S_LEN 2048
#define NB 64
#define HD 256

static __device__ __forceinline__ unsigned int pk16(float a, float b) {
  half2v h; h[0] = (_Float16)a; h[1] = (_Float16)b;
  return __builtin_bit_cast(unsigned int, h);
}
static __device__ __forceinline__ float uph(unsigned short u) {
  return (float)__builtin_bit_cast(_Float16, u);
}
static __device__ __forceinline__ float dot2a(unsigned int h2, unsigned int w2, float acc) {
  return __builtin_amdgcn_fdot2(__builtin_bit_cast(half2v, h2),
                                __builtin_bit_cast(half2v, w2), acc, false);
}
static __device__ __forceinline__ float sigm(float x) {
  return 1.0f / (1.0f + __expf(-x));
}
static __device__ __forceinline__ float tanh_fast(float x) {
  float e = __expf(2.0f * x);
  return 1.0f - 2.0f / (e + 1.0f);   // safe at +/-inf
}

// ---------------------------------------------------------------------------
// Kernel 1: P[m, g*256+j] = f16( x[m,:] . W{g}_x[j,:] + b{g}[j] )
// m = s*64+b in [0,131072), tiles 128x128, BK=64, fp16 MFMA.
// ---------------------------------------------------------------------------
__global__ __launch_bounds__(256, 2) void gemm_pre(
    const float* __restrict__ x,
    const float* __restrict__ Wz, const float* __restrict__ bz,
    const float* __restrict__ Wr, const float* __restrict__ br,
    const float* __restrict__ Wc, const float* __restrict__ bc,
    const float* __restrict__ Wh, const float* __restrict__ bh,
    unsigned short* __restrict__ P)
{
  __shared__ __align__(16) char As[128 * 128];   // 128 rows x 64 f16 (swizzled)
  __shared__ __align__(16) char Bs[128 * 128];
  const int t = threadIdx.x;
  const int lane = t & 63;
  const int wid = t >> 6;
  const int wm = wid >> 1, wn = wid & 1;
  const int n0 = blockIdx.x * 128;
  const int m0 = blockIdx.y * 128;

  f32x4 acc[4][4];
  #pragma unroll
  for (int i = 0; i < 4; ++i)
    #pragma unroll
    for (int jq = 0; jq < 4; ++jq) acc[i][jq] = f32x4{0.f, 0.f, 0.f, 0.f};

  for (int kk = 0; kk < 4; ++kk) {
    __syncthreads();
    #pragma unroll
    for (int it = 0; it < 8; ++it) {
      int fl = it * 256 + t;
      int row = fl >> 4;
      int c4 = fl & 15;
      f32x4 v = *(const f32x4*)(x + (size_t)(m0 + row) * 256 + kk * 64 + c4 * 4);
      uint2 pw; pw.x = pk16(v[0], v[1]); pw.y = pk16(v[2], v[3]);
      *(uint2*)(As + row * 128 + ((c4 * 8) ^ ((row & 7) << 4))) = pw;

      int n = n0 + row;
      int g = n >> 8; int jc = n & 255;
      const float* W = (g == 0) ? Wz : (g == 1) ? Wr : (g == 2) ? Wc : Wh;
      f32x4 w = *(const f32x4*)(W + jc * 512 + kk * 64 + c4 * 4);
      uint2 qw; qw.x = pk16(w[0], w[1]); qw.y = pk16(w[2], w[3]);
      *(uint2*)(Bs + row * 128 + ((c4 * 8) ^ ((row & 7) << 4))) = qw;
    }
    __syncthreads();
    #pragma unroll
    for (int k2 = 0; k2 < 2; ++k2) {
      const int kb = k2 * 64 + (lane >> 4) * 16;
      half8v a[4], bfr[4];
      #pragma unroll
      for (int i = 0; i < 4; ++i) {
        int ar = wm * 64 + i * 16 + (lane & 15);
        a[i] = *(const half8v*)(As + ar * 128 + (kb ^ ((ar & 7) << 4)));
        int br2 = wn * 64 + i * 16 + (lane & 15);
        bfr[i] = *(const half8v*)(Bs + br2 * 128 + (kb ^ ((br2 & 7) << 4)));
      }
      #pragma unroll
      for (int i = 0; i < 4; ++i)
        #pragma unroll
        for (int jq = 0; jq < 4; ++jq)
          acc[i][jq] = __builtin_amdgcn_mfma_f32_16x16x32_f16(a[i], bfr[jq], acc[i][jq], 0, 0, 0);
    }
  }
  // epilogue: +bias, f16 store. C/D: col=lane&15, row=(lane>>4)*4+r  [m89]
  #pragma unroll
  for (int jq = 0; jq < 4; ++jq) {
    int col = n0 + wn * 64 + jq * 16 + (lane & 15);
    int g = col >> 8; int jc = col & 255;
    const float* bp = (g == 0) ? bz : (g == 1) ? br : (g == 2) ? bc : bh;
    float bias = bp[jc];
    #pragma unroll
    for (int i = 0; i < 4; ++i) {
      int rowb = m0 + wm * 64 + i * 16 + (lane >> 4) * 4;
      #pragma unroll
      for (int r = 0; r < 4; ++r) {
        float vv = acc[i][jq][r] + bias;
        _Float16 hh = (_Float16)vv;
        P[(size_t)(rowb + r) * 1024 + col] = __builtin_bit_cast(unsigned short, hh);
      }
    }
  }
}

// ---------------------------------------------------------------------------
// Kernel 2: persistent recurrent scan. 64 blocks (one chain each) x 512 thr.
// t<256: z-row t in regs; t>=256: r-row (t-256) in regs; all: g half-row in
// regs; Wc in swizzled LDS. h state: fp32 in reg (owner thread) + f16 in LDS.
// ---------------------------------------------------------------------------
__global__ __launch_bounds__(512, 2) void gru_scan(
    const float* __restrict__ Wz, const float* __restrict__ Wr,
    const float* __restrict__ Wc, const float* __restrict__ Wh,
    const float* __restrict__ gamma, const float* __restrict__ beta,
    const unsigned short* __restrict__ P,
    float* __restrict__ out)
{
  __shared__ __align__(16) char c_lds[256 * 512];   // Wc as f16, swizzled
  __shared__ __align__(16) unsigned int hf16[128];  // h as f16 pairs
  __shared__ __align__(16) unsigned int rh16[128];  // r*h as f16 pairs
  __shared__ float rp[256];
  __shared__ float gp[256];
  __shared__ float cp[256];
  __shared__ float2 red[4];

  const int t = threadIdx.x;
  const int b = blockIdx.x;
  const int j = t & 255;
  const int jj = t >> 1;
  const int hf = t & 1;

  unsigned int wrow[128];
  {
    const float* src = ((t < 256) ? Wz : Wr) + j * 512 + 256;
    #pragma unroll
    for (int i = 0; i < 64; ++i) {
      f32x4 v = *(const f32x4*)(src + i * 4);
      wrow[2 * i] = pk16(v[0], v[1]);
      wrow[2 * i + 1] = pk16(v[2], v[3]);
    }
  }
  unsigned int wgh[64];
  {
    const float* src = Wh + jj * 512 + 256 + hf * 128;
    #pragma unroll
    for (int i = 0; i < 32; ++i) {
      f32x4 v = *(const f32x4*)(src + i * 4);
      wgh[2 * i] = pk16(v[0], v[1]);
      wgh[2 * i + 1] = pk16(v[2], v[3]);
    }
  }
  #pragma unroll 4
  for (int it = 0; it < 32; ++it) {   // stage Wc -> LDS (swizzled)
    int fl = it * 512 + t;
    int row = fl >> 6;
    int c4 = fl & 63;
    f32x4 v = *(const f32x4*)(Wc + row * 512 + 256 + c4 * 4);
    uint2 pw; pw.x = pk16(v[0], v[1]); pw.y = pk16(v[2], v[3]);
    *(uint2*)(c_lds + row * 512 + ((c4 * 8) ^ ((row & 15) << 4))) = pw;
  }
  if (t < 128) hf16[t] = 0u;
  float h_own = 0.0f;
  float gam = 0.f, bet = 0.f;
  if (t < 256) { gam = gamma[j]; bet = beta[j]; }

  unsigned short czx = 0, crx = 0, ccx = 0, cgx = 0;
  if (t < 256) {
    const unsigned short* pb = P + (size_t)b * 1024;
    czx = pb[j]; crx = pb[256 + j]; ccx = pb[512 + j]; cgx = pb[768 + j];
  }
  __syncthreads();

  float zval = 0.f;
  #pragma unroll 1
  for (int s = 0; s < S_LEN; ++s) {
    unsigned short nzx = 0, nrx = 0, ncx = 0, ngx = 0;
    if (t < 256 && s + 1 < S_LEN) {          // prefetch next step's preacts
      const unsigned short* pb = P + ((size_t)(s + 1) * 64 + b) * 1024;
      nzx = pb[j]; nrx = pb[256 + j]; ncx = pb[512 + j]; ngx = pb[768 + j];
    }
    // A: matvecs from h (z or r full row; g half row)
    float accA = 0.f;
    #pragma unroll
    for (int q = 0; q < 32; ++q) {
      uint4 hv = *(const uint4*)&hf16[q * 4];
      accA = dot2a(hv.x, wrow[4 * q + 0], accA);
      accA = dot2a(hv.y, wrow[4 * q + 1], accA);
      accA = dot2a(hv.z, wrow[4 * q + 2], accA);
      accA = dot2a(hv.w, wrow[4 * q + 3], accA);
    }
    float accG = 0.f;
    {
      const unsigned int* hb = hf16 + hf * 64;
      #pragma unroll
      for (int q = 0; q < 16; ++q) {
        uint4 hv = *(const uint4*)&hb[q * 4];
        accG = dot2a(hv.x, wgh[4 * q + 0], accG);
        accG = dot2a(hv.y, wgh[4 * q + 1], accG);
        accG = dot2a(hv.z, wgh[4 * q + 2], accG);
        accG = dot2a(hv.w, wgh[4 * q + 3], accG);
      }
    }
    accG += __shfl_xor(accG, 1);
    if (t >= 256) rp[j] = accA;
    if (hf == 0) gp[jj] = accG;
    __syncthreads();                                   // (1)
    // B: r, rh
    if (t < 256) {
      float r = sigm(rp[j] + uph(crx));
      float rh = r * h_own;
      ((unsigned short*)rh16)[j] = __builtin_bit_cast(unsigned short, (_Float16)rh);
      zval = sigm(accA + uph(czx));
    }
    __syncthreads();                                   // (2)
    // C: c matvec from rh (weights in swizzled LDS)
    float accC = 0.f;
    {
      const char* crow = c_lds + jj * 512;
      const unsigned int* rb = rh16 + hf * 64;
      #pragma unroll
      for (int i2 = 0; i2 < 16; ++i2) {
        uint4 wv = *(const uint4*)(crow + (((hf << 8) + (i2 << 4)) ^ ((jj & 15) << 4)));
        uint4 rv = *(const uint4*)&rb[i2 * 4];
        accC = dot2a(rv.x, wv.x, accC);
        accC = dot2a(rv.y, wv.y, accC);
        accC = dot2a(rv.z, wv.z, accC);
        accC = dot2a(rv.w, wv.w, accC);
      }
    }
    accC += __shfl_xor(accC, 1);
    if (hf == 0) cp[jj] = accC;
    __syncthreads();                                   // (3)
    // D: combine + LN
    float hfin = 0.f;
    if (t < 256) {
      float ht = tanh_fast(cp[j] + uph(ccx));
      float gt = sigm(gp[j] + uph(cgx));
      float hn = (1.0f - zval) * h_own + zval * ht;
      hfin = gt * hn + (1.0f - gt) * h_own;
      h_own = hn;
      ((unsigned short*)hf16)[j] = __builtin_bit_cast(unsigned short, (_Float16)hn);
      float s1 = hfin, s2 = hfin * hfin;
      #pragma unroll
      for (int off = 1; off < 64; off <<= 1) {
        s1 += __shfl_xor(s1, off);
        s2 += __shfl_xor(s2, off);
      }
      if ((t & 63) == 0) red[t >> 6] = make_float2(s1, s2);
    }
    __syncthreads();                                   // (4)
    if (t < 256) {
      float S1 = red[0].x + red[1].x + red[2].x + red[3].x;
      float S2 = red[0].y + red[1].y + red[2].y + red[3].y;
      float mu = S1 * (1.0f / 256.0f);
      float var = S2 * (1.0f / 256.0f) - mu * mu;
      float rs = rsqrtf(var + 1e-5f);
      out[(size_t)s * 16384 + b * 256 + j] = (hfin - mu) * rs * gam + bet;
    }
    czx = nzx; crx = nrx; ccx = ncx; cgx = ngx;
  }
  if (t < 256) out[(size_t)33554432 + b * 256 + j] = h_own;
}

extern "C" void kernel_launch(void* const* d_in, const int* in_sizes, int n_in,
                              void* d_out, int out_size, void* d_ws, size_t ws_size,
                              hipStream_t stream) {
  const float* x  = (const float*)d_in[0];
  const float* Wz = (const float*)d_in[1];
  const float* bz = (const float*)d_in[2];
  const float* Wr = (const float*)d_in[3];
  const float* br = (const float*)d_in[4];
  const float* Wc = (const float*)d_in[5];
  const float* bc = (const float*)d_in[6];
  const float* Wh = (const float*)d_in[7];
  const float* bh = (const float*)d_in[8];
  const float* gamma = (const float*)d_in[9];
  const float* beta  = (const float*)d_in[10];
  unsigned short* P = (unsigned short*)d_ws;   // 131072 x 1024 f16 = 256 MB
  float* out = (float*)d_out;

  dim3 g1(8, 1024);                 // n-tiles x m-tiles
  gemm_pre<<<g1, 256, 0, stream>>>(x, Wz, bz, Wr, br, Wc, bc, Wh, bh, P);
  gru_scan<<<64, 512, 0, stream>>>(Wz, Wr, Wc, Wh, gamma, beta, P, out);
}